// Round 5
// baseline (414.572 us; speedup 1.0000x reference)
//
#include <hip/hip_runtime.h>
#include <math.h>

// Problem constants
#define R_   1152
#define C_   10
#define D_   16
#define I_   8
#define B_   256
#define N_   160      // C_*D_ (n = c*16+d)
#define K_   9216     // R_*I_ (k = r*8+i)
#define KS_  32       // K-split across blocks
#define KC_  288      // K_/KS_ per block
#define KW_  72       // per-wave k slice (KC_/4)

// workspace layout (float offsets)
#define OFF_WT    0                      // 1,474,560  WT0[k][n] (plain transpose)
#define OFF_WSUM  1474560                //    92,160  Wsum[r][c][i]
#define OFF_TT    (OFF_WSUM + 92160)     // 2,949,120  tT[c][b][r]
#define OFF_V     (OFF_TT + 2949120)     //    40,960  v[b][n]
#define OFF_BIJ   (OFF_V + 40960)        //   184,320  bij[r][n]
#define OFF_E     (OFF_BIJ + 184320)     //   184,320  E[r][n] = exp(bij)
#define OFF_NSA   (OFF_E + 184320)       //       160  nsumA
#define OFF_NSB   (OFF_NSA + 160)        //       160  nsumB
#define OFF_CNT   (OFF_NSB + 160)        //        64  (ints; lastblock counters)
#define OFF_PART  (OFF_CNT + 64)         // 1,310,720  partials[ks][b][n]

// ---------------------------------------------------------------------------
// prep: blocks [0,360): Wsum[r,c,i] = sum_d W[r,c,d,i]
//       blocks [360,1800): WT0[k][n] = W[r][n][i]  (k = r*8+i)
//       block 1800: zero cnt + nsumA + nsumB
__global__ void prep_kernel(const float* __restrict__ W, float* __restrict__ Wsum,
                            float* __restrict__ WT, float* __restrict__ nsumA,
                            float* __restrict__ nsumB, int* __restrict__ cnt) {
    int bid = blockIdx.x, tid = threadIdx.x;
    if (bid == 1800) {
        if (tid < 48) cnt[tid] = 0;
        if (tid < N_) { nsumA[tid] = 0.0f; nsumB[tid] = 0.0f; }
        return;
    }
    if (bid < 360) {
        int idx = bid * 256 + tid;                     // 92160 exact
        int r = idx / (C_ * I_);
        int rem = idx % (C_ * I_);
        int c = rem / I_;
        int i = rem % I_;
        const float* p = W + (size_t)r * (C_ * D_ * I_) + c * (D_ * I_) + i;
        float s = 0.0f;
#pragma unroll
        for (int d = 0; d < D_; ++d) s += p[d * I_];
        Wsum[idx] = s;
    } else {
        int q = (bid - 360) * 256 + tid;               // 368640 = K_*N_/4 exact
        int k = q / (N_ / 4);
        int n4 = (q % (N_ / 4)) * 4;
        int r = k >> 3, i = k & 7;
        const float* wp = W + (size_t)r * (C_ * D_ * I_) + n4 * I_ + i;
        float4 o;
        o.x = wp[0]; o.y = wp[8]; o.z = wp[16]; o.w = wp[24];
        ((float4*)WT)[q] = o;
    }
}

// ---------------------------------------------------------------------------
// GEMM + lastblock squash finalize; optional E-weighting; optional fused t-phase.
// blocks [0,512): s_partial[ks][b][n] = sum_k u[b][k] * WT0[k][n] * (E ? E[r][n] : 1)
//   32nd-arriving ks block per bt: s = sum_ks partials; s = nsum ? s/nsum[n] : s*scale;
//   dst = squash(s).
// blocks [512,872) (do_t only): tT[c][b][r] = sum_i Wsum[r,c,i]*u[b,r,i]
__launch_bounds__(256)
__global__ void gemm_kernel(const float* __restrict__ u, const float* __restrict__ WT,
                            const float* __restrict__ E, const float* __restrict__ nsum,
                            float* __restrict__ partials, int* __restrict__ cnt,
                            float* __restrict__ dst, float scale,
                            const float* __restrict__ Wsum, float* __restrict__ tT) {
    int bid = blockIdx.x, tid = threadIdx.x;
    if (bid >= 512) {                                   // fused t-phase
        for (int idx = (bid - 512) * 256 + tid; idx < B_ * R_; idx += 360 * 256) {
            int r = idx % R_;
            int b = idx / R_;
            const float4* up = (const float4*)(u + (size_t)idx * I_);
            float4 a0 = up[0], a1 = up[1];
            const float* wp = Wsum + (size_t)r * (C_ * I_);
            float outv[C_];
#pragma unroll
            for (int c = 0; c < C_; ++c) {
                const float4* w4 = (const float4*)(wp + c * I_);
                float4 w0 = w4[0], w1 = w4[1];
                outv[c] = a0.x * w0.x + a0.y * w0.y + a0.z * w0.z + a0.w * w0.w
                        + a1.x * w1.x + a1.y * w1.y + a1.z * w1.z + a1.w * w1.w;
            }
#pragma unroll
            for (int c = 0; c < C_; ++c)
                tT[((size_t)c * B_ + b) * R_ + r] = outv[c];
        }
        return;
    }

    __shared__ float red[4 * 2560];
    __shared__ int flag;
    int wave = tid >> 6, lane = tid & 63;
    int ng = lane & 15, bg = lane >> 4;
    int ks = bid & 31, bt = bid >> 5;                  // 32 ks x 16 bt
    int b0 = bt * 16;
    int kbase = ks * KC_ + wave * KW_;                 // multiple of 8
    int n0 = ng * 10;

    float acc[4][10];
#pragma unroll
    for (int m = 0; m < 4; ++m)
#pragma unroll
        for (int j = 0; j < 10; ++j) acc[m][j] = 0.0f;

    const float* ur[4];
#pragma unroll
    for (int m = 0; m < 4; ++m) ur[m] = u + (size_t)(b0 + bg * 4 + m) * K_;

    float e[10];
    for (int kk = 0; kk < KW_; kk += 4) {
        int k = kbase + kk;
        if (E != nullptr && (kk & 7) == 0) {           // new r-group every 8 k
            const float* ep = E + (size_t)(k >> 3) * N_ + n0;
#pragma unroll
            for (int j = 0; j < 10; j += 2) {
                float2 ee = *(const float2*)(ep + j);
                e[j] = ee.x; e[j + 1] = ee.y;
            }
        }
        float ua[4][4];
#pragma unroll
        for (int m = 0; m < 4; ++m) {
            float4 tmp = *(const float4*)(ur[m] + k);
            ua[m][0] = tmp.x; ua[m][1] = tmp.y; ua[m][2] = tmp.z; ua[m][3] = tmp.w;
        }
#pragma unroll
        for (int t4 = 0; t4 < 4; ++t4) {
            const float* wrow = WT + (size_t)(k + t4) * N_ + n0;
            float w[10];
#pragma unroll
            for (int j = 0; j < 10; j += 2) {
                float2 ww = *(const float2*)(wrow + j);
                w[j] = ww.x; w[j + 1] = ww.y;
            }
            if (E != nullptr) {
#pragma unroll
                for (int j = 0; j < 10; ++j) w[j] *= e[j];
            }
#pragma unroll
            for (int m = 0; m < 4; ++m)
#pragma unroll
                for (int j = 0; j < 10; ++j)
                    acc[m][j] = fmaf(ua[m][t4], w[j], acc[m][j]);
        }
    }

    // cross-wave reduce + partials store
#pragma unroll
    for (int m = 0; m < 4; ++m)
#pragma unroll
        for (int j = 0; j < 10; ++j)
            red[wave * 2560 + (bg * 4 + m) * N_ + n0 + j] = acc[m][j];
    __syncthreads();
    float* outp = partials + (size_t)ks * (B_ * N_) + (size_t)b0 * N_;
    for (int f = tid; f < 2560; f += 256)
        outp[f] = red[f] + red[2560 + f] + red[5120 + f] + red[7680 + f];

    // lastblock finalize (threadfence-reduction; validated pattern)
    __threadfence();
    __syncthreads();
    if (tid == 0) flag = (atomicAdd(&cnt[bt], 1) == KS_ - 1) ? 1 : 0;
    __syncthreads();
    if (flag) {
        __threadfence();
        for (int f = tid; f < 2560; f += 256) {
            int g = b0 * N_ + f;
            float s = 0.0f;
#pragma unroll
            for (int ksi = 0; ksi < KS_; ++ksi)
                s += partials[(size_t)ksi * (B_ * N_) + g];
            s = (nsum != nullptr) ? (s / nsum[f % N_]) : (s * scale);
            float sq = s * s;
            dst[g] = sq / (1.0f + sq) * s / (sqrtf(sq) + 1e-5f);
        }
    }
}

// ---------------------------------------------------------------------------
// bij[r][n] (+)= (1/B) * sum_b v[b][n] * tT[c][b][r]
// E[r][n] = exp(bij[r][n]);  nsum[n] += sum_r E[r][n]   (max-free softmax)
__launch_bounds__(256)
__global__ void bupd_kernel(const float* __restrict__ v, const float* __restrict__ tT,
                            float* __restrict__ bij, float* __restrict__ E,
                            float* __restrict__ nsum, int accumulate) {
    __shared__ float vs[B_ * 16];     // [b][d] 16 KB
    __shared__ float red[16 * 256];   // [d][tid] 16 KB
    int tid = threadIdx.x;
    int c = blockIdx.x % 10;
    int r0 = (blockIdx.x / 10) * 64;
    int rsub = tid & 63, bs = tid >> 6;

    for (int q = tid; q < 1024; q += 256) {
        int b = q >> 2, d4 = q & 3;
        ((float4*)vs)[q] = *(const float4*)(v + (size_t)b * N_ + c * 16 + d4 * 4);
    }
    __syncthreads();

    float acc[16];
#pragma unroll
    for (int d = 0; d < 16; ++d) acc[d] = 0.0f;

    const float* tp = tT + ((size_t)c * B_ + bs * 64) * R_ + r0 + rsub;
    for (int bb = 0; bb < 64; ++bb) {
        float tv = tp[(size_t)bb * R_];                       // coalesced
        const float4* vrow = (const float4*)(vs + (bs * 64 + bb) * 16);
        float4 v0 = vrow[0], v1 = vrow[1], v2 = vrow[2], v3 = vrow[3];
        acc[0]  = fmaf(tv, v0.x, acc[0]);  acc[1]  = fmaf(tv, v0.y, acc[1]);
        acc[2]  = fmaf(tv, v0.z, acc[2]);  acc[3]  = fmaf(tv, v0.w, acc[3]);
        acc[4]  = fmaf(tv, v1.x, acc[4]);  acc[5]  = fmaf(tv, v1.y, acc[5]);
        acc[6]  = fmaf(tv, v1.z, acc[6]);  acc[7]  = fmaf(tv, v1.w, acc[7]);
        acc[8]  = fmaf(tv, v2.x, acc[8]);  acc[9]  = fmaf(tv, v2.y, acc[9]);
        acc[10] = fmaf(tv, v2.z, acc[10]); acc[11] = fmaf(tv, v2.w, acc[11]);
        acc[12] = fmaf(tv, v3.x, acc[12]); acc[13] = fmaf(tv, v3.y, acc[13]);
        acc[14] = fmaf(tv, v3.z, acc[14]); acc[15] = fmaf(tv, v3.w, acc[15]);
    }
#pragma unroll
    for (int d = 0; d < 16; ++d) red[d * 256 + tid] = acc[d];
    __syncthreads();

#pragma unroll
    for (int j = 0; j < 4; ++j) {
        int q = tid + 256 * j;
        int rr = q & 63, d = q >> 6;                 // d uniform per wave
        const float* rp = red + d * 256 + rr;
        float s = (rp[0] + rp[64] + rp[128] + rp[192]) * (1.0f / B_);
        int o = (r0 + rr) * N_ + c * 16 + d;
        if (accumulate) s += bij[o];
        bij[o] = s;
        float ex = __expf(s);                         // max-free: |bij| = O(1)
        E[o] = ex;
#pragma unroll
        for (int off = 32; off > 0; off >>= 1) ex += __shfl_down(ex, off, 64);
        if (rr == 0) atomicAdd(&nsum[c * 16 + d], ex);
    }
}

// ---------------------------------------------------------------------------
extern "C" void kernel_launch(void* const* d_in, const int* in_sizes, int n_in,
                              void* d_out, int out_size, void* d_ws, size_t ws_size,
                              hipStream_t stream) {
    (void)in_sizes; (void)n_in; (void)out_size; (void)ws_size;
    const float* u = (const float*)d_in[0];
    const float* W = (const float*)d_in[1];
    float* out = (float*)d_out;
    float* ws = (float*)d_ws;

    float* WT       = ws + OFF_WT;
    float* Wsum     = ws + OFF_WSUM;
    float* tT       = ws + OFF_TT;
    float* v        = ws + OFF_V;
    float* bij      = ws + OFF_BIJ;
    float* E        = ws + OFF_E;
    float* nsumA    = ws + OFF_NSA;
    float* nsumB    = ws + OFF_NSB;
    int*   cnt      = (int*)(ws + OFF_CNT);
    float* partials = ws + OFF_PART;

    // 6 dispatches total
    prep_kernel<<<1801, 256, 0, stream>>>(W, Wsum, WT, nsumA, nsumB, cnt);

    // iter 0: uniform softmax (1/1152), fused t-phase; finalize -> v
    gemm_kernel<<<872, 256, 0, stream>>>(u, WT, nullptr, nullptr, partials,
                                         cnt + 0, v, 1.0f / 1152.0f, Wsum, tT);
    bupd_kernel<<<180, 256, 0, stream>>>(v, tT, bij, E, nsumA, 0);

    // iter 1: E-weighted gemm, finalize divides by nsumA -> v
    gemm_kernel<<<512, 256, 0, stream>>>(u, WT, E, nsumA, partials,
                                         cnt + 16, v, 1.0f, nullptr, nullptr);
    bupd_kernel<<<180, 256, 0, stream>>>(v, tT, bij, E, nsumB, 1);

    // iter 2: E-weighted gemm, finalize divides by nsumB -> out
    gemm_kernel<<<512, 256, 0, stream>>>(u, WT, E, nsumB, partials,
                                         cnt + 32, out, 1.0f, nullptr, nullptr);
}

// Round 6
// 240.846 us; speedup vs baseline: 1.7213x; 1.7213x over previous
//
#include <hip/hip_runtime.h>
#include <math.h>

// Problem constants
#define R_   1152
#define C_   10
#define D_   16
#define I_   8
#define B_   256
#define N_   160      // C_*D_ (n = c*16+d)
#define K_   9216     // R_*I_ (k = r*8+i)
#define KS_  32       // K-split across blocks
#define KC_  288      // K_/KS_ per block
#define KW_  72       // per-wave k slice (KC_/4)

// workspace layout (float offsets); ~13 MB
#define OFF_WT    0                      // 1,474,560  WT0[k][n] (plain transpose)
#define OFF_WSUM  1474560                //    92,160  Wsum[r][c][i]
#define OFF_BIJ   (OFF_WSUM + 92160)     //   184,320  bij[r][n]
#define OFF_E     (OFF_BIJ + 184320)     //   184,320  E[r][n] = exp(bij)
#define OFF_NSA   (OFF_E + 184320)       //       160  nsumA
#define OFF_NSB   (OFF_NSA + 160)        //       160  nsumB
#define OFF_PART  (OFF_NSB + 160)        // 1,310,720  partials[ks][b][n]

// ---------------------------------------------------------------------------
// prep: blocks [0,360): Wsum[r,c,i] = sum_d W[r,c,d,i]
//       blocks [360,1800): WT0[k][n] = W[r][n][i]  (k = r*8+i)
//       block 1800: zero nsumA + nsumB
__global__ void prep_kernel(const float* __restrict__ W, float* __restrict__ Wsum,
                            float* __restrict__ WT, float* __restrict__ nsumA,
                            float* __restrict__ nsumB) {
    int bid = blockIdx.x, tid = threadIdx.x;
    if (bid == 1800) {
        if (tid < N_) { nsumA[tid] = 0.0f; nsumB[tid] = 0.0f; }
        return;
    }
    if (bid < 360) {
        int idx = bid * 256 + tid;                     // 92160 exact
        int r = idx / (C_ * I_);
        int rem = idx % (C_ * I_);
        int c = rem / I_;
        int i = rem % I_;
        const float* p = W + (size_t)r * (C_ * D_ * I_) + c * (D_ * I_) + i;
        float s = 0.0f;
#pragma unroll
        for (int d = 0; d < D_; ++d) s += p[d * I_];
        Wsum[idx] = s;
    } else {
        int q = (bid - 360) * 256 + tid;               // 368640 = K_*N_/4 exact
        int k = q / (N_ / 4);
        int n4 = (q % (N_ / 4)) * 4;
        int r = k >> 3, i = k & 7;
        const float* wp = W + (size_t)r * (C_ * D_ * I_) + n4 * I_ + i;
        float4 o;
        o.x = wp[0]; o.y = wp[8]; o.z = wp[16]; o.w = wp[24];
        ((float4*)WT)[q] = o;
    }
}

// ---------------------------------------------------------------------------
// partials[ks][b*160+n] = sum_{k in slice} u[b][k] * WT[k][n] * cweight
// where cweight = E[r(k)][n]/nsum[n] when E!=null, else 1.
// No fences, no finalize — the next dispatch consumes partials.
__launch_bounds__(256)
__global__ void gemm_kernel(const float* __restrict__ u, const float* __restrict__ WT,
                            const float* __restrict__ E, const float* __restrict__ nsum,
                            float* __restrict__ partials) {
    __shared__ float red[4 * 2560];
    int tid = threadIdx.x;
    int wave = tid >> 6, lane = tid & 63;
    int ng = lane & 15, bg = lane >> 4;
    int ks = blockIdx.x & 31, bt = blockIdx.x >> 5;    // 32 ks x 16 bt
    int b0 = bt * 16;
    int kbase = ks * KC_ + wave * KW_;                 // multiple of 8
    int n0 = ng * 10;

    float inv[10];
    if (E != nullptr) {
#pragma unroll
        for (int j = 0; j < 10; ++j) inv[j] = 1.0f / nsum[n0 + j];
    }

    float acc[4][10];
#pragma unroll
    for (int m = 0; m < 4; ++m)
#pragma unroll
        for (int j = 0; j < 10; ++j) acc[m][j] = 0.0f;

    const float* ur[4];
#pragma unroll
    for (int m = 0; m < 4; ++m) ur[m] = u + (size_t)(b0 + bg * 4 + m) * K_;

    float e[10];
    for (int kk = 0; kk < KW_; kk += 4) {
        int k = kbase + kk;
        if (E != nullptr && (kk & 7) == 0) {           // new r-group every 8 k
            const float* ep = E + (size_t)(k >> 3) * N_ + n0;
#pragma unroll
            for (int j = 0; j < 10; j += 2) {
                float2 ee = *(const float2*)(ep + j);
                e[j] = ee.x * inv[j]; e[j + 1] = ee.y * inv[j + 1];
            }
        }
        float ua[4][4];
#pragma unroll
        for (int m = 0; m < 4; ++m) {
            float4 tmp = *(const float4*)(ur[m] + k);
            ua[m][0] = tmp.x; ua[m][1] = tmp.y; ua[m][2] = tmp.z; ua[m][3] = tmp.w;
        }
#pragma unroll
        for (int t4 = 0; t4 < 4; ++t4) {
            const float* wrow = WT + (size_t)(k + t4) * N_ + n0;
            float w[10];
#pragma unroll
            for (int j = 0; j < 10; j += 2) {
                float2 ww = *(const float2*)(wrow + j);
                w[j] = ww.x; w[j + 1] = ww.y;
            }
            if (E != nullptr) {
#pragma unroll
                for (int j = 0; j < 10; ++j) w[j] *= e[j];
            }
#pragma unroll
            for (int m = 0; m < 4; ++m)
#pragma unroll
                for (int j = 0; j < 10; ++j)
                    acc[m][j] = fmaf(ua[m][t4], w[j], acc[m][j]);
        }
    }

    // cross-wave reduce + partials store (coalesced)
#pragma unroll
    for (int m = 0; m < 4; ++m)
#pragma unroll
        for (int j = 0; j < 10; ++j)
            red[wave * 2560 + (bg * 4 + m) * N_ + n0 + j] = acc[m][j];
    __syncthreads();
    float* outp = partials + (size_t)ks * (B_ * N_) + (size_t)b0 * N_;
    for (int f = tid; f < 2560; f += 256)
        outp[f] = red[f] + red[2560 + f] + red[5120 + f] + red[7680 + f];
}

// ---------------------------------------------------------------------------
// bupd: per block (c, r0-tile of 64):
//   vs[b][d] = squash(scale * sum_ks partials[ks][b][c*16+d])   (inline v)
//   t[b][r]  = sum_i Wsum[r][c][i] * u[b][r][i]                 (on the fly)
//   bij[r][n] (+)= (1/B) sum_b vs[b][d] * t[b][r]
//   E[r][n] = exp(bij); nsum[n] += sum_r E (max-free softmax)
__launch_bounds__(256)
__global__ void bupd_kernel(const float* __restrict__ u, const float* __restrict__ Wsum,
                            const float* __restrict__ partials, float scale,
                            float* __restrict__ bij, float* __restrict__ E,
                            float* __restrict__ nsum, int accumulate) {
    __shared__ float vs[B_ * 16];     // [b][d] 16 KB
    __shared__ float red[16 * 256];   // [d][tid] 16 KB
    int tid = threadIdx.x;
    int c = blockIdx.x % 10;
    int r0 = (blockIdx.x / 10) * 64;
    int rsub = tid & 63, bs = tid >> 6;
    int r = r0 + rsub;

    // inline v: sum 32 partial slices, squash
    for (int q = tid; q < 1024; q += 256) {
        int b = q >> 2, d4 = q & 3;
        const float4* pp = (const float4*)(partials + (size_t)b * N_ + c * 16 + d4 * 4);
        float4 a = {0.0f, 0.0f, 0.0f, 0.0f};
#pragma unroll
        for (int ks = 0; ks < KS_; ++ks) {
            float4 p = pp[(size_t)ks * (B_ * N_ / 4)];
            a.x += p.x; a.y += p.y; a.z += p.z; a.w += p.w;
        }
        float4 o;
        {
            float s = a.x * scale; float sq = s * s;
            o.x = sq / (1.0f + sq) * s / (sqrtf(sq) + 1e-5f);
            s = a.y * scale; sq = s * s;
            o.y = sq / (1.0f + sq) * s / (sqrtf(sq) + 1e-5f);
            s = a.z * scale; sq = s * s;
            o.z = sq / (1.0f + sq) * s / (sqrtf(sq) + 1e-5f);
            s = a.w * scale; sq = s * s;
            o.w = sq / (1.0f + sq) * s / (sqrtf(sq) + 1e-5f);
        }
        ((float4*)vs)[q] = o;
    }
    __syncthreads();

    // per-thread Wsum row (c fixed): 8 floats
    const float4* wsp = (const float4*)(Wsum + ((size_t)r * C_ + c) * I_);
    float4 ws0 = wsp[0], ws1 = wsp[1];

    float acc[16];
#pragma unroll
    for (int d = 0; d < 16; ++d) acc[d] = 0.0f;

    for (int bb = 0; bb < 64; ++bb) {
        int b = bs * 64 + bb;                          // wave-uniform
        const float4* up = (const float4*)(u + ((size_t)b * R_ + r) * I_);
        float4 u0 = up[0], u1 = up[1];                 // coalesced across rsub
        float tv = u0.x * ws0.x + u0.y * ws0.y + u0.z * ws0.z + u0.w * ws0.w
                 + u1.x * ws1.x + u1.y * ws1.y + u1.z * ws1.z + u1.w * ws1.w;
        const float4* vrow = (const float4*)(vs + b * 16);  // wave-uniform broadcast
        float4 v0 = vrow[0], v1 = vrow[1], v2 = vrow[2], v3 = vrow[3];
        acc[0]  = fmaf(tv, v0.x, acc[0]);  acc[1]  = fmaf(tv, v0.y, acc[1]);
        acc[2]  = fmaf(tv, v0.z, acc[2]);  acc[3]  = fmaf(tv, v0.w, acc[3]);
        acc[4]  = fmaf(tv, v1.x, acc[4]);  acc[5]  = fmaf(tv, v1.y, acc[5]);
        acc[6]  = fmaf(tv, v1.z, acc[6]);  acc[7]  = fmaf(tv, v1.w, acc[7]);
        acc[8]  = fmaf(tv, v2.x, acc[8]);  acc[9]  = fmaf(tv, v2.y, acc[9]);
        acc[10] = fmaf(tv, v2.z, acc[10]); acc[11] = fmaf(tv, v2.w, acc[11]);
        acc[12] = fmaf(tv, v3.x, acc[12]); acc[13] = fmaf(tv, v3.y, acc[13]);
        acc[14] = fmaf(tv, v3.z, acc[14]); acc[15] = fmaf(tv, v3.w, acc[15]);
    }
#pragma unroll
    for (int d = 0; d < 16; ++d) red[d * 256 + tid] = acc[d];
    __syncthreads();

#pragma unroll
    for (int j = 0; j < 4; ++j) {
        int q = tid + 256 * j;
        int rr = q & 63, d = q >> 6;                   // d uniform per wave
        const float* rp = red + d * 256 + rr;
        float s = (rp[0] + rp[64] + rp[128] + rp[192]) * (1.0f / B_);
        int o = (r0 + rr) * N_ + c * 16 + d;
        if (accumulate) s += bij[o];
        bij[o] = s;
        float ex = __expf(s);                          // max-free: |bij| = O(1)
        E[o] = ex;
#pragma unroll
        for (int off = 32; off > 0; off >>= 1) ex += __shfl_down(ex, off, 64);
        if (rr == 0) atomicAdd(&nsum[c * 16 + d], ex);
    }
}

// ---------------------------------------------------------------------------
// out = squash(sum_ks partials)   (gemm2's partials already c_ij-weighted)
__global__ void rs_kernel(const float* __restrict__ partials, float* __restrict__ out) {
    int g = blockIdx.x * 256 + threadIdx.x;            // 160 blocks -> 40960 exact
    float s = 0.0f;
#pragma unroll
    for (int ks = 0; ks < KS_; ++ks) s += partials[(size_t)ks * (B_ * N_) + g];
    float sq = s * s;
    out[g] = sq / (1.0f + sq) * s / (sqrtf(sq) + 1e-5f);
}

// ---------------------------------------------------------------------------
extern "C" void kernel_launch(void* const* d_in, const int* in_sizes, int n_in,
                              void* d_out, int out_size, void* d_ws, size_t ws_size,
                              hipStream_t stream) {
    (void)in_sizes; (void)n_in; (void)out_size; (void)ws_size;
    const float* u = (const float*)d_in[0];
    const float* W = (const float*)d_in[1];
    float* out = (float*)d_out;
    float* ws = (float*)d_ws;

    float* WT       = ws + OFF_WT;
    float* Wsum     = ws + OFF_WSUM;
    float* bij      = ws + OFF_BIJ;
    float* E        = ws + OFF_E;
    float* nsumA    = ws + OFF_NSA;
    float* nsumB    = ws + OFF_NSB;
    float* partials = ws + OFF_PART;

    // 7 dispatches
    prep_kernel<<<1801, 256, 0, stream>>>(W, Wsum, WT, nsumA, nsumB);

    gemm_kernel<<<512, 256, 0, stream>>>(u, WT, nullptr, nullptr, partials);
    bupd_kernel<<<180, 256, 0, stream>>>(u, Wsum, partials, 1.0f / 1152.0f,
                                         bij, E, nsumA, 0);

    gemm_kernel<<<512, 256, 0, stream>>>(u, WT, E, nsumA, partials);
    bupd_kernel<<<180, 256, 0, stream>>>(u, Wsum, partials, 1.0f,
                                         bij, E, nsumB, 1);

    gemm_kernel<<<512, 256, 0, stream>>>(u, WT, E, nsumB, partials);
    rs_kernel<<<160, 256, 0, stream>>>(partials, out);
}

// Round 7
// 214.239 us; speedup vs baseline: 1.9351x; 1.1242x over previous
//
#include <hip/hip_runtime.h>
#include <math.h>

// Problem constants
#define R_   1152
#define C_   10
#define D_   16
#define I_   8
#define B_   256
#define N_   160      // C_*D_ (n = c*16+d)
#define K_   9216     // R_*I_ (k = r*8+i)
#define KS_  32       // K-split across blocks
#define KC_  288      // K_/KS_ per block (9 chunks of 32)

// workspace layout (float offsets); ~13 MB
#define OFF_WT    0                      // 1,474,560  WT0[k][n] (plain transpose)
#define OFF_WSUM  1474560                //    92,160  Wsum[r][c][i]
#define OFF_BIJ   (OFF_WSUM + 92160)     //   184,320  bij[r][n]
#define OFF_E     (OFF_BIJ + 184320)     //   184,320  E[r][n] = exp(bij)
#define OFF_NSA   (OFF_E + 184320)       //       160  nsumA
#define OFF_NSB   (OFF_NSA + 160)        //       160  nsumB
#define OFF_PART  (OFF_NSB + 160)        // 1,310,720  partials[ks][b][n]

// ---------------------------------------------------------------------------
// prep: blocks [0,360): Wsum[r,c,i] = sum_d W[r,c,d,i]
//       blocks [360,1800): WT0[k][n] = W[r][n][i]  (k = r*8+i)
//       block 1800: zero nsumA + nsumB
__global__ void prep_kernel(const float* __restrict__ W, float* __restrict__ Wsum,
                            float* __restrict__ WT, float* __restrict__ nsumA,
                            float* __restrict__ nsumB) {
    int bid = blockIdx.x, tid = threadIdx.x;
    if (bid == 1800) {
        if (tid < N_) { nsumA[tid] = 0.0f; nsumB[tid] = 0.0f; }
        return;
    }
    if (bid < 360) {
        int idx = bid * 256 + tid;                     // 92160 exact
        int r = idx / (C_ * I_);
        int rem = idx % (C_ * I_);
        int c = rem / I_;
        int i = rem % I_;
        const float* p = W + (size_t)r * (C_ * D_ * I_) + c * (D_ * I_) + i;
        float s = 0.0f;
#pragma unroll
        for (int d = 0; d < D_; ++d) s += p[d * I_];
        Wsum[idx] = s;
    } else {
        int q = (bid - 360) * 256 + tid;               // 368640 = K_*N_/4 exact
        int k = q / (N_ / 4);
        int n4 = (q % (N_ / 4)) * 4;
        int r = k >> 3, i = k & 7;
        const float* wp = W + (size_t)r * (C_ * D_ * I_) + n4 * I_ + i;
        float4 o;
        o.x = wp[0]; o.y = wp[8]; o.z = wp[16]; o.w = wp[24];
        ((float4*)WT)[q] = o;
    }
}

// ---------------------------------------------------------------------------
// partials[ks][b*160+n] = sum_{k in slice} u[b][k] * WT[k][n] * cweight
// cweight = E[r(k)][n]/nsum[n] when E!=null else 1 — folded into LDS staging.
// B-operand staged per 32k x 160n chunk into LDS (coalesced float4), inner
// loop reads conflict-free ds_read; removes the fragmented float2 global
// reads that made the unstaged version TA-bound (R5: VALUBusy 5.5%).
__launch_bounds__(256)
__global__ void gemm_kernel(const float* __restrict__ u, const float* __restrict__ WT,
                            const float* __restrict__ E, const float* __restrict__ nsum,
                            float* __restrict__ partials) {
    __shared__ float smem[10240];   // 40 KB: [0,5120) chunk; [5120,5160) inv; reduce uses all
    float* chunk = smem;
    float* invs  = smem + 5120;     // 160 floats, dead by reduce time
    int tid = threadIdx.x;
    int wave = tid >> 6, lane = tid & 63;
    int ng = lane & 15, bg = lane >> 4;
    int ks = blockIdx.x & 31, bt = blockIdx.x >> 5;    // 32 ks x 16 bt
    int b0 = bt * 16;
    int kblk = ks * KC_;
    int n0 = ng * 10;

    if (E != nullptr && tid < N_) invs[tid] = 1.0f / nsum[tid];

    float acc[4][10];
#pragma unroll
    for (int m = 0; m < 4; ++m)
#pragma unroll
        for (int j = 0; j < 10; ++j) acc[m][j] = 0.0f;

    const float* ur[4];
#pragma unroll
    for (int m = 0; m < 4; ++m) ur[m] = u + (size_t)(b0 + bg * 4 + m) * K_;

    for (int c = 0; c < 9; ++c) {
        int k0 = kblk + c * 32;
        __syncthreads();                               // chunk free (also covers invs init)
        // stage chunk: LDS[kk][n] = WT[k0+kk][n] * (E ? E[r][n]*inv[n] : 1)
        if (E != nullptr) {
#pragma unroll
            for (int it = 0; it < 5; ++it) {
                int q = tid + it * 256;                // 1280 float4 exact
                int kk = q / 40, n4 = q % 40;
                int k = k0 + kk;
                float4 wv = *(const float4*)(WT + (size_t)k * N_ + n4 * 4);
                float4 ev = *(const float4*)(E + (size_t)(k >> 3) * N_ + n4 * 4);
                float4 iv = ((const float4*)invs)[n4];
                wv.x *= ev.x * iv.x; wv.y *= ev.y * iv.y;
                wv.z *= ev.z * iv.z; wv.w *= ev.w * iv.w;
                ((float4*)chunk)[q] = wv;
            }
        } else {
            const float4* src = (const float4*)(WT + (size_t)k0 * N_);
#pragma unroll
            for (int it = 0; it < 5; ++it) {
                int q = tid + it * 256;
                ((float4*)chunk)[q] = src[q];
            }
        }
        __syncthreads();

        // compute: wave handles chunk rows [wave*8, wave*8+8)
#pragma unroll
        for (int g = 0; g < 2; ++g) {
            int kl = wave * 8 + g * 4;
            int kabs = k0 + kl;
            float ua[4][4];
#pragma unroll
            for (int m = 0; m < 4; ++m) {
                float4 tmp = *(const float4*)(ur[m] + kabs);
                ua[m][0] = tmp.x; ua[m][1] = tmp.y; ua[m][2] = tmp.z; ua[m][3] = tmp.w;
            }
#pragma unroll
            for (int t4 = 0; t4 < 4; ++t4) {
                const float* wrow = chunk + (kl + t4) * N_ + n0;
                float w[10];
#pragma unroll
                for (int j = 0; j < 10; j += 2) {
                    float2 ww = *(const float2*)(wrow + j);   // conflict-free ds_read_b64
                    w[j] = ww.x; w[j + 1] = ww.y;
                }
#pragma unroll
                for (int m = 0; m < 4; ++m)
#pragma unroll
                    for (int j = 0; j < 10; ++j)
                        acc[m][j] = fmaf(ua[m][t4], w[j], acc[m][j]);
            }
        }
    }

    // cross-wave reduce + partials store (coalesced); smem reused as 40 KB arena
    __syncthreads();
#pragma unroll
    for (int m = 0; m < 4; ++m)
#pragma unroll
        for (int j = 0; j < 10; ++j)
            smem[wave * 2560 + (bg * 4 + m) * N_ + n0 + j] = acc[m][j];
    __syncthreads();
    float* outp = partials + (size_t)ks * (B_ * N_) + (size_t)b0 * N_;
    for (int f = tid; f < 2560; f += 256)
        outp[f] = smem[f] + smem[2560 + f] + smem[5120 + f] + smem[7680 + f];
}

// ---------------------------------------------------------------------------
// bupd: per block (c, r0-tile of 64):
//   vs[b][d] = squash(scale * sum_ks partials[ks][b][c*16+d])   (inline v)
//   t[b][r]  = sum_i Wsum[r][c][i] * u[b][r][i]                 (on the fly)
//   bij[r][n] (+)= (1/B) sum_b vs[b][d] * t[b][r]
//   E[r][n] = exp(bij); nsum[n] += sum_r E (max-free softmax)
__launch_bounds__(256)
__global__ void bupd_kernel(const float* __restrict__ u, const float* __restrict__ Wsum,
                            const float* __restrict__ partials, float scale,
                            float* __restrict__ bij, float* __restrict__ E,
                            float* __restrict__ nsum, int accumulate) {
    __shared__ float vs[B_ * 16];     // [b][d] 16 KB
    __shared__ float red[16 * 256];   // [d][tid] 16 KB
    int tid = threadIdx.x;
    int c = blockIdx.x % 10;
    int r0 = (blockIdx.x / 10) * 64;
    int rsub = tid & 63, bs = tid >> 6;
    int r = r0 + rsub;

    // inline v: sum 32 partial slices, squash
    for (int q = tid; q < 1024; q += 256) {
        int b = q >> 2, d4 = q & 3;
        const float4* pp = (const float4*)(partials + (size_t)b * N_ + c * 16 + d4 * 4);
        float4 a = {0.0f, 0.0f, 0.0f, 0.0f};
#pragma unroll
        for (int ks = 0; ks < KS_; ++ks) {
            float4 p = pp[(size_t)ks * (B_ * N_ / 4)];
            a.x += p.x; a.y += p.y; a.z += p.z; a.w += p.w;
        }
        float4 o;
        {
            float s = a.x * scale; float sq = s * s;
            o.x = sq / (1.0f + sq) * s / (sqrtf(sq) + 1e-5f);
            s = a.y * scale; sq = s * s;
            o.y = sq / (1.0f + sq) * s / (sqrtf(sq) + 1e-5f);
            s = a.z * scale; sq = s * s;
            o.z = sq / (1.0f + sq) * s / (sqrtf(sq) + 1e-5f);
            s = a.w * scale; sq = s * s;
            o.w = sq / (1.0f + sq) * s / (sqrtf(sq) + 1e-5f);
        }
        ((float4*)vs)[q] = o;
    }
    __syncthreads();

    // per-thread Wsum row (c fixed): 8 floats
    const float4* wsp = (const float4*)(Wsum + ((size_t)r * C_ + c) * I_);
    float4 ws0 = wsp[0], ws1 = wsp[1];

    float acc[16];
#pragma unroll
    for (int d = 0; d < 16; ++d) acc[d] = 0.0f;

    for (int bb = 0; bb < 64; ++bb) {
        int b = bs * 64 + bb;                          // wave-uniform
        const float4* up = (const float4*)(u + ((size_t)b * R_ + r) * I_);
        float4 u0 = up[0], u1 = up[1];
        float tv = u0.x * ws0.x + u0.y * ws0.y + u0.z * ws0.z + u0.w * ws0.w
                 + u1.x * ws1.x + u1.y * ws1.y + u1.z * ws1.z + u1.w * ws1.w;
        const float4* vrow = (const float4*)(vs + b * 16);  // wave-uniform broadcast
        float4 v0 = vrow[0], v1 = vrow[1], v2 = vrow[2], v3 = vrow[3];
        acc[0]  = fmaf(tv, v0.x, acc[0]);  acc[1]  = fmaf(tv, v0.y, acc[1]);
        acc[2]  = fmaf(tv, v0.z, acc[2]);  acc[3]  = fmaf(tv, v0.w, acc[3]);
        acc[4]  = fmaf(tv, v1.x, acc[4]);  acc[5]  = fmaf(tv, v1.y, acc[5]);
        acc[6]  = fmaf(tv, v1.z, acc[6]);  acc[7]  = fmaf(tv, v1.w, acc[7]);
        acc[8]  = fmaf(tv, v2.x, acc[8]);  acc[9]  = fmaf(tv, v2.y, acc[9]);
        acc[10] = fmaf(tv, v2.z, acc[10]); acc[11] = fmaf(tv, v2.w, acc[11]);
        acc[12] = fmaf(tv, v3.x, acc[12]); acc[13] = fmaf(tv, v3.y, acc[13]);
        acc[14] = fmaf(tv, v3.z, acc[14]); acc[15] = fmaf(tv, v3.w, acc[15]);
    }
#pragma unroll
    for (int d = 0; d < 16; ++d) red[d * 256 + tid] = acc[d];
    __syncthreads();

#pragma unroll
    for (int j = 0; j < 4; ++j) {
        int q = tid + 256 * j;
        int rr = q & 63, d = q >> 6;                   // d uniform per wave
        const float* rp = red + d * 256 + rr;
        float s = (rp[0] + rp[64] + rp[128] + rp[192]) * (1.0f / B_);
        int o = (r0 + rr) * N_ + c * 16 + d;
        if (accumulate) s += bij[o];
        bij[o] = s;
        float ex = __expf(s);                          // max-free: |bij| = O(1)
        E[o] = ex;
#pragma unroll
        for (int off = 32; off > 0; off >>= 1) ex += __shfl_down(ex, off, 64);
        if (rr == 0) atomicAdd(&nsum[c * 16 + d], ex);
    }
}

// ---------------------------------------------------------------------------
// out = squash(sum_ks partials)   (gemm2's partials already c_ij-weighted)
__global__ void rs_kernel(const float* __restrict__ partials, float* __restrict__ out) {
    int g = blockIdx.x * 256 + threadIdx.x;            // 160 blocks -> 40960 exact
    float s = 0.0f;
#pragma unroll
    for (int ks = 0; ks < KS_; ++ks) s += partials[(size_t)ks * (B_ * N_) + g];
    float sq = s * s;
    out[g] = sq / (1.0f + sq) * s / (sqrtf(sq) + 1e-5f);
}

// ---------------------------------------------------------------------------
extern "C" void kernel_launch(void* const* d_in, const int* in_sizes, int n_in,
                              void* d_out, int out_size, void* d_ws, size_t ws_size,
                              hipStream_t stream) {
    (void)in_sizes; (void)n_in; (void)out_size; (void)ws_size;
    const float* u = (const float*)d_in[0];
    const float* W = (const float*)d_in[1];
    float* out = (float*)d_out;
    float* ws = (float*)d_ws;

    float* WT       = ws + OFF_WT;
    float* Wsum     = ws + OFF_WSUM;
    float* bij      = ws + OFF_BIJ;
    float* E        = ws + OFF_E;
    float* nsumA    = ws + OFF_NSA;
    float* nsumB    = ws + OFF_NSB;
    float* partials = ws + OFF_PART;

    // 7 dispatches
    prep_kernel<<<1801, 256, 0, stream>>>(W, Wsum, WT, nsumA, nsumB);

    gemm_kernel<<<512, 256, 0, stream>>>(u, WT, nullptr, nullptr, partials);
    bupd_kernel<<<180, 256, 0, stream>>>(u, Wsum, partials, 1.0f / 1152.0f,
                                         bij, E, nsumA, 0);

    gemm_kernel<<<512, 256, 0, stream>>>(u, WT, E, nsumA, partials);
    bupd_kernel<<<180, 256, 0, stream>>>(u, Wsum, partials, 1.0f,
                                         bij, E, nsumB, 1);

    gemm_kernel<<<512, 256, 0, stream>>>(u, WT, E, nsumB, partials);
    rs_kernel<<<160, 256, 0, stream>>>(partials, out);
}

// Round 8
// 207.650 us; speedup vs baseline: 1.9965x; 1.0317x over previous
//
#include <hip/hip_runtime.h>
#include <math.h>

// Problem constants
#define R_   1152
#define C_   10
#define D_   16
#define I_   8
#define B_   256
#define N_   160      // C_*D_ (n = c*16+d)
#define K_   9216     // R_*I_ (k = r*8+i)
#define KS_  32       // K-split across blocks
#define KC_  288      // K_/KS_ per block (9 chunks of 32 k = 4 r-rows)

// workspace layout (float offsets); ~6.8 MB
#define OFF_BIJ   0                      //   184,320  bij[r][n]
#define OFF_E     184320                 //   184,320  E[r][n] = exp(bij)
#define OFF_NSA   (OFF_E + 184320)       //       160  nsumA
#define OFF_NSB   (OFF_NSA + 160)        //       160  nsumB
#define OFF_PART  (OFF_NSB + 160)        // 1,310,720  partials[ks][b][n]

// ---------------------------------------------------------------------------
// GEMM: partials[ks][b*160+n] = sum_{k slice} u[b][k] * W[r][n][i] * cw
//   cw = E[r][n]/nsum[n] (HASE) else 1.
// Barrier-free K-loop: wave w's chunk quarter (8 k-rows = one W r-row) is
// PRIVATE — staged from W (1280 contiguous floats, coalesced f4) into its own
// LDS region, transposed via 2-way-conflict-free ds_write_b32, software-
// pipelined: fetch regs for chunk c+1 overlaps compute of chunk c. No
// __syncthreads until the epilogue cross-wave reduce.
template <int HASE>
__launch_bounds__(256)
__global__ void gemm_kernel(const float* __restrict__ u, const float* __restrict__ W,
                            const float* __restrict__ E, const float* __restrict__ nsum,
                            float* __restrict__ partials,
                            float* __restrict__ zA, float* __restrict__ zB) {
    __shared__ float smem[10240];   // 40 KB: [0,5120) = 4 wave-quarters; reduce reuses all
    int tid = threadIdx.x;
    int wave = tid >> 6, lane = tid & 63;
    int ng = lane & 15, bg = lane >> 4;
    int ks = blockIdx.x & 31, bt = blockIdx.x >> 5;    // 32 ks x 16 bt
    int b0 = bt * 16;
    int n0 = ng * 10;

    if (!HASE && blockIdx.x == 0 && tid < N_) { zA[tid] = 0.0f; zB[tid] = 0.0f; }

    float acc[4][10];
#pragma unroll
    for (int m = 0; m < 4; ++m)
#pragma unroll
        for (int j = 0; j < 10; ++j) acc[m][j] = 0.0f;

    const float* ur[4];
#pragma unroll
    for (int m = 0; m < 4; ++m) ur[m] = u + (size_t)(b0 + bg * 4 + m) * K_;

    // prefetch chunk 0: lane l, it: idx = it*64+l; n = idx>>1; i-half = (idx&1)*4
    float4 wr[5];
    float  ee[5];
    {
        int r = ks * 36 + wave;                        // chunk 0
#pragma unroll
        for (int it = 0; it < 5; ++it) {
            int idx = it * 64 + lane;
            wr[it] = *(const float4*)(W + (size_t)r * 1280 + idx * 4);
            if (HASE) {
                int n = idx >> 1;
                ee[it] = E[r * N_ + n] / nsum[n];
            }
        }
    }

    int ldsbase = wave * 1280;
    for (int c = 0; c < 9; ++c) {
        // stage chunk c from regs into private quarter (transpose i into rows)
#pragma unroll
        for (int it = 0; it < 5; ++it) {
            int idx = it * 64 + lane;
            int n = idx >> 1, ih = (idx & 1) * 4;
            float e = HASE ? ee[it] : 1.0f;
            float* q = &smem[ldsbase + ih * 160 + n];
            q[0]   = wr[it].x * e;
            q[160] = wr[it].y * e;
            q[320] = wr[it].z * e;
            q[480] = wr[it].w * e;
        }
        // prefetch chunk c+1 (clamped refetch on last iter keeps pipeline uniform)
        {
            int cn = (c + 1 < 9) ? (c + 1) : 0;
            int r = ks * 36 + cn * 4 + wave;
#pragma unroll
            for (int it = 0; it < 5; ++it) {
                int idx = it * 64 + lane;
                wr[it] = *(const float4*)(W + (size_t)r * 1280 + idx * 4);
                if (HASE) {
                    int n = idx >> 1;
                    ee[it] = E[r * N_ + n] / nsum[n];
                }
            }
        }
        // compute chunk c (ds_reads of own quarter; overlaps the prefetch)
#pragma unroll
        for (int g = 0; g < 2; ++g) {
            int kabs = ks * KC_ + c * 32 + wave * 8 + g * 4;
            float ua[4][4];
#pragma unroll
            for (int m = 0; m < 4; ++m) {
                float4 tmp = *(const float4*)(ur[m] + kabs);
                ua[m][0] = tmp.x; ua[m][1] = tmp.y; ua[m][2] = tmp.z; ua[m][3] = tmp.w;
            }
#pragma unroll
            for (int t4 = 0; t4 < 4; ++t4) {
                const float* wrow = &smem[ldsbase + (g * 4 + t4) * 160 + n0];
                float w[10];
#pragma unroll
                for (int j = 0; j < 10; j += 2) {
                    float2 ww = *(const float2*)(wrow + j);   // conflict-free b64
                    w[j] = ww.x; w[j + 1] = ww.y;
                }
#pragma unroll
                for (int m = 0; m < 4; ++m)
#pragma unroll
                    for (int j = 0; j < 10; ++j)
                        acc[m][j] = fmaf(ua[m][t4], w[j], acc[m][j]);
            }
        }
    }

    // epilogue: cross-wave reduce (40 KB arena reuses quarters -> barrier first)
    __syncthreads();
#pragma unroll
    for (int m = 0; m < 4; ++m)
#pragma unroll
        for (int j = 0; j < 10; ++j)
            smem[wave * 2560 + (bg * 4 + m) * N_ + n0 + j] = acc[m][j];
    __syncthreads();
    float* outp = partials + (size_t)ks * (B_ * N_) + (size_t)b0 * N_;
    for (int f = tid; f < 2560; f += 256)
        outp[f] = smem[f] + smem[2560 + f] + smem[5120 + f] + smem[7680 + f];
}

// ---------------------------------------------------------------------------
// bupd: per block (c, r0-tile of 64):
//   vs[b][d] = squash(scale * sum_ks partials[ks][b][c*16+d])
//   ws[i]    = sum_d W[r][c][d][i]            (on the fly; no Wsum pass)
//   t[b][r]  = sum_i ws[i] * u[b][r][i]
//   bij[r][n] (+)= (1/B) sum_b vs[b][d] * t[b][r]
//   E[r][n] = exp(bij); nsum[n] += sum_r E   (max-free softmax)
__launch_bounds__(256)
__global__ void bupd_kernel(const float* __restrict__ u, const float* __restrict__ W,
                            const float* __restrict__ partials, float scale,
                            float* __restrict__ bij, float* __restrict__ E,
                            float* __restrict__ nsum, int accumulate) {
    __shared__ float vs[B_ * 16];     // [b][d] 16 KB
    __shared__ float red[16 * 256];   // [d][tid] 16 KB
    int tid = threadIdx.x;
    int c = blockIdx.x % 10;
    int r0 = (blockIdx.x / 10) * 64;
    int rsub = tid & 63, bs = tid >> 6;
    int r = r0 + rsub;

    // inline v: sum 32 partial slices, squash
    for (int q = tid; q < 1024; q += 256) {
        int b = q >> 2, d4 = q & 3;
        const float4* pp = (const float4*)(partials + (size_t)b * N_ + c * 16 + d4 * 4);
        float4 a = {0.0f, 0.0f, 0.0f, 0.0f};
#pragma unroll
        for (int ks = 0; ks < KS_; ++ks) {
            float4 p = pp[(size_t)ks * (B_ * N_ / 4)];
            a.x += p.x; a.y += p.y; a.z += p.z; a.w += p.w;
        }
        float4 o;
        {
            float s = a.x * scale; float sq = s * s;
            o.x = sq / (1.0f + sq) * s / (sqrtf(sq) + 1e-5f);
            s = a.y * scale; sq = s * s;
            o.y = sq / (1.0f + sq) * s / (sqrtf(sq) + 1e-5f);
            s = a.z * scale; sq = s * s;
            o.z = sq / (1.0f + sq) * s / (sqrtf(sq) + 1e-5f);
            s = a.w * scale; sq = s * s;
            o.w = sq / (1.0f + sq) * s / (sqrtf(sq) + 1e-5f);
        }
        ((float4*)vs)[q] = o;
    }
    __syncthreads();

    // on-the-fly Wsum row: ws[i] = sum_d W[r][c][d][i]
    const float* wrow = W + ((size_t)r * C_ + c) * (D_ * I_);
    float4 ws0 = {0.0f, 0.0f, 0.0f, 0.0f}, ws1 = {0.0f, 0.0f, 0.0f, 0.0f};
#pragma unroll
    for (int d = 0; d < D_; ++d) {
        float4 a = *(const float4*)(wrow + d * I_);
        float4 b = *(const float4*)(wrow + d * I_ + 4);
        ws0.x += a.x; ws0.y += a.y; ws0.z += a.z; ws0.w += a.w;
        ws1.x += b.x; ws1.y += b.y; ws1.z += b.z; ws1.w += b.w;
    }

    float acc[16];
#pragma unroll
    for (int d = 0; d < 16; ++d) acc[d] = 0.0f;

    for (int bb = 0; bb < 64; ++bb) {
        int b = bs * 64 + bb;                          // wave-uniform
        const float4* up = (const float4*)(u + ((size_t)b * R_ + r) * I_);
        float4 u0 = up[0], u1 = up[1];                 // coalesced across rsub
        float tv = u0.x * ws0.x + u0.y * ws0.y + u0.z * ws0.z + u0.w * ws0.w
                 + u1.x * ws1.x + u1.y * ws1.y + u1.z * ws1.z + u1.w * ws1.w;
        const float4* vrow = (const float4*)(vs + b * 16);  // wave-uniform broadcast
        float4 v0 = vrow[0], v1 = vrow[1], v2 = vrow[2], v3 = vrow[3];
        acc[0]  = fmaf(tv, v0.x, acc[0]);  acc[1]  = fmaf(tv, v0.y, acc[1]);
        acc[2]  = fmaf(tv, v0.z, acc[2]);  acc[3]  = fmaf(tv, v0.w, acc[3]);
        acc[4]  = fmaf(tv, v1.x, acc[4]);  acc[5]  = fmaf(tv, v1.y, acc[5]);
        acc[6]  = fmaf(tv, v1.z, acc[6]);  acc[7]  = fmaf(tv, v1.w, acc[7]);
        acc[8]  = fmaf(tv, v2.x, acc[8]);  acc[9]  = fmaf(tv, v2.y, acc[9]);
        acc[10] = fmaf(tv, v2.z, acc[10]); acc[11] = fmaf(tv, v2.w, acc[11]);
        acc[12] = fmaf(tv, v3.x, acc[12]); acc[13] = fmaf(tv, v3.y, acc[13]);
        acc[14] = fmaf(tv, v3.z, acc[14]); acc[15] = fmaf(tv, v3.w, acc[15]);
    }
#pragma unroll
    for (int d = 0; d < 16; ++d) red[d * 256 + tid] = acc[d];
    __syncthreads();

#pragma unroll
    for (int j = 0; j < 4; ++j) {
        int q = tid + 256 * j;
        int rr = q & 63, d = q >> 6;                   // d uniform per wave
        const float* rp = red + d * 256 + rr;
        float s = (rp[0] + rp[64] + rp[128] + rp[192]) * (1.0f / B_);
        int o = (r0 + rr) * N_ + c * 16 + d;
        if (accumulate) s += bij[o];
        bij[o] = s;
        float ex = __expf(s);                          // max-free: |bij| = O(1)
        E[o] = ex;
#pragma unroll
        for (int off = 32; off > 0; off >>= 1) ex += __shfl_down(ex, off, 64);
        if (rr == 0) atomicAdd(&nsum[c * 16 + d], ex);
    }
}

// ---------------------------------------------------------------------------
// out = squash(sum_ks partials)   (gemm2's partials already c_ij-weighted)
__global__ void rs_kernel(const float* __restrict__ partials, float* __restrict__ out) {
    int g = blockIdx.x * 256 + threadIdx.x;            // 160 blocks -> 40960 exact
    float s = 0.0f;
#pragma unroll
    for (int ks = 0; ks < KS_; ++ks) s += partials[(size_t)ks * (B_ * N_) + g];
    float sq = s * s;
    out[g] = sq / (1.0f + sq) * s / (sqrtf(sq) + 1e-5f);
}

// ---------------------------------------------------------------------------
extern "C" void kernel_launch(void* const* d_in, const int* in_sizes, int n_in,
                              void* d_out, int out_size, void* d_ws, size_t ws_size,
                              hipStream_t stream) {
    (void)in_sizes; (void)n_in; (void)out_size; (void)ws_size;
    const float* u = (const float*)d_in[0];
    const float* W = (const float*)d_in[1];
    float* out = (float*)d_out;
    float* ws = (float*)d_ws;

    float* bij      = ws + OFF_BIJ;
    float* E        = ws + OFF_E;
    float* nsumA    = ws + OFF_NSA;
    float* nsumB    = ws + OFF_NSB;
    float* partials = ws + OFF_PART;

    // 6 dispatches
    gemm_kernel<0><<<512, 256, 0, stream>>>(u, W, nullptr, nullptr, partials,
                                            nsumA, nsumB);
    bupd_kernel<<<180, 256, 0, stream>>>(u, W, partials, 1.0f / 1152.0f,
                                         bij, E, nsumA, 0);

    gemm_kernel<1><<<512, 256, 0, stream>>>(u, W, E, nsumA, partials,
                                            nsumA, nsumB);
    bupd_kernel<<<180, 256, 0, stream>>>(u, W, partials, 1.0f,
                                         bij, E, nsumB, 1);

    gemm_kernel<1><<<512, 256, 0, stream>>>(u, W, E, nsumB, partials,
                                            nsumA, nsumB);
    rs_kernel<<<160, 256, 0, stream>>>(partials, out);
}

// Round 9
// 179.636 us; speedup vs baseline: 2.3079x; 1.1560x over previous
//
#include <hip/hip_runtime.h>
#include <math.h>

// Problem constants
#define R_   1152
#define C_   10
#define D_   16
#define I_   8
#define B_   256
#define N_   160      // C_*D_ (n = c*16+d)
#define K_   9216     // R_*I_ (k = r*8+i)
#define KS_  32       // K-split across blocks
#define KC_  288      // K_/KS_ per block (9 chunks of 32 k = 4 r-rows)

// workspace layout (float offsets); ~19 MB
#define OFF_WSUM  0                      //    92,160  Wsum[r][c][i]
#define OFF_TT    92160                  // 2,949,120  tT[c][b][r]
#define OFF_V     (OFF_TT + 2949120)     //    40,960  v[b][n]
#define OFF_BIJ   (OFF_V + 40960)        //   184,320  bij[r][n]
#define OFF_E     (OFF_BIJ + 184320)     //   184,320  E[r][n] = exp(bij)
#define OFF_NSA   (OFF_E + 184320)       //       160  nsumA
#define OFF_NSB   (OFF_NSA + 160)        //       160  nsumB
#define OFF_PART  (OFF_NSB + 160)        // 1,310,720  partials[ks][b][n]

// ---------------------------------------------------------------------------
// GEMM: partials[ks][b*160+n] = sum_{k slice} u[b][k] * W[r][n][i] * cw
//   cw = E[r][n]/nsum[n] (HASE) else 1.
// Barrier-free pipelined K-loop (R8-proven, ~6 us). When !HASE, extra blocks
// [512,872) compute Wsum[r,c,i] = sum_d W[r,c,d,i]; block 0 zeros nsums.
template <int HASE>
__launch_bounds__(256)
__global__ void gemm_kernel(const float* __restrict__ u, const float* __restrict__ W,
                            const float* __restrict__ E, const float* __restrict__ nsum,
                            float* __restrict__ partials, float* __restrict__ Wsum,
                            float* __restrict__ zA, float* __restrict__ zB) {
    int tid = threadIdx.x;
    if (!HASE && blockIdx.x >= 512) {                  // fused Wsum pass
        int idx = (blockIdx.x - 512) * 256 + tid;      // 360 blocks -> 92160 exact
        int r = idx / (C_ * I_);
        int rem = idx % (C_ * I_);
        int c = rem / I_;
        int i = rem % I_;
        const float* p = W + (size_t)r * (C_ * D_ * I_) + c * (D_ * I_) + i;
        float s = 0.0f;
#pragma unroll
        for (int d = 0; d < D_; ++d) s += p[d * I_];
        Wsum[idx] = s;
        return;
    }

    __shared__ float smem[10240];   // 40 KB: [0,5120) = 4 wave-quarters; reduce reuses all
    int wave = tid >> 6, lane = tid & 63;
    int ng = lane & 15, bg = lane >> 4;
    int ks = blockIdx.x & 31, bt = blockIdx.x >> 5;    // 32 ks x 16 bt
    int b0 = bt * 16;
    int n0 = ng * 10;

    if (!HASE && blockIdx.x == 0 && tid < N_) { zA[tid] = 0.0f; zB[tid] = 0.0f; }

    float acc[4][10];
#pragma unroll
    for (int m = 0; m < 4; ++m)
#pragma unroll
        for (int j = 0; j < 10; ++j) acc[m][j] = 0.0f;

    const float* ur[4];
#pragma unroll
    for (int m = 0; m < 4; ++m) ur[m] = u + (size_t)(b0 + bg * 4 + m) * K_;

    // prefetch chunk 0
    float4 wr[5];
    float  ee[5];
    {
        int r = ks * 36 + wave;
#pragma unroll
        for (int it = 0; it < 5; ++it) {
            int idx = it * 64 + lane;
            wr[it] = *(const float4*)(W + (size_t)r * 1280 + idx * 4);
            if (HASE) {
                int n = idx >> 1;
                ee[it] = E[r * N_ + n] / nsum[n];
            }
        }
    }

    int ldsbase = wave * 1280;
    for (int c = 0; c < 9; ++c) {
        // stage chunk c into private wave quarter
#pragma unroll
        for (int it = 0; it < 5; ++it) {
            int idx = it * 64 + lane;
            int n = idx >> 1, ih = (idx & 1) * 4;
            float e = HASE ? ee[it] : 1.0f;
            float* q = &smem[ldsbase + ih * 160 + n];
            q[0]   = wr[it].x * e;
            q[160] = wr[it].y * e;
            q[320] = wr[it].z * e;
            q[480] = wr[it].w * e;
        }
        // prefetch chunk c+1
        {
            int cn = (c + 1 < 9) ? (c + 1) : 0;
            int r = ks * 36 + cn * 4 + wave;
#pragma unroll
            for (int it = 0; it < 5; ++it) {
                int idx = it * 64 + lane;
                wr[it] = *(const float4*)(W + (size_t)r * 1280 + idx * 4);
                if (HASE) {
                    int n = idx >> 1;
                    ee[it] = E[r * N_ + n] / nsum[n];
                }
            }
        }
        // compute chunk c
#pragma unroll
        for (int g = 0; g < 2; ++g) {
            int kabs = ks * KC_ + c * 32 + wave * 8 + g * 4;
            float ua[4][4];
#pragma unroll
            for (int m = 0; m < 4; ++m) {
                float4 tmp = *(const float4*)(ur[m] + kabs);
                ua[m][0] = tmp.x; ua[m][1] = tmp.y; ua[m][2] = tmp.z; ua[m][3] = tmp.w;
            }
#pragma unroll
            for (int t4 = 0; t4 < 4; ++t4) {
                const float* wrow = &smem[ldsbase + (g * 4 + t4) * 160 + n0];
                float w[10];
#pragma unroll
                for (int j = 0; j < 10; j += 2) {
                    float2 ww = *(const float2*)(wrow + j);
                    w[j] = ww.x; w[j + 1] = ww.y;
                }
#pragma unroll
                for (int m = 0; m < 4; ++m)
#pragma unroll
                    for (int j = 0; j < 10; ++j)
                        acc[m][j] = fmaf(ua[m][t4], w[j], acc[m][j]);
            }
        }
    }

    // epilogue: cross-wave reduce
    __syncthreads();
#pragma unroll
    for (int m = 0; m < 4; ++m)
#pragma unroll
        for (int j = 0; j < 10; ++j)
            smem[wave * 2560 + (bg * 4 + m) * N_ + n0 + j] = acc[m][j];
    __syncthreads();
    float* outp = partials + (size_t)ks * (B_ * N_) + (size_t)b0 * N_;
    for (int f = tid; f < 2560; f += 256)
        outp[f] = smem[f] + smem[2560 + f] + smem[5120 + f] + smem[7680 + f];
}

// ---------------------------------------------------------------------------
// rsv: blocks [0,160): dst[g] = squash(scale * sum_ks partials[ks][g])
//      blocks [160,520) (DOT only): tT[c][b][r] = sum_i Wsum[r,c,i]*u[b,r,i]
template <int DOT>
__global__ void rsv_kernel(const float* __restrict__ partials, float* __restrict__ dst,
                           float scale, const float* __restrict__ u,
                           const float* __restrict__ Wsum, float* __restrict__ tT) {
    int tid = threadIdx.x;
    if (DOT && blockIdx.x >= 160) {                    // fused t-pass
        for (int idx = (blockIdx.x - 160) * 256 + tid; idx < B_ * R_; idx += 360 * 256) {
            int r = idx % R_;
            int b = idx / R_;
            const float4* up = (const float4*)(u + (size_t)idx * I_);
            float4 a0 = up[0], a1 = up[1];
            const float* wp = Wsum + (size_t)r * (C_ * I_);
            float outv[C_];
#pragma unroll
            for (int c = 0; c < C_; ++c) {
                const float4* w4 = (const float4*)(wp + c * I_);
                float4 w0 = w4[0], w1 = w4[1];
                outv[c] = a0.x * w0.x + a0.y * w0.y + a0.z * w0.z + a0.w * w0.w
                        + a1.x * w1.x + a1.y * w1.y + a1.z * w1.z + a1.w * w1.w;
            }
#pragma unroll
            for (int c = 0; c < C_; ++c)
                tT[((size_t)c * B_ + b) * R_ + r] = outv[c];   // coalesced in r
        }
        return;
    }
    int g = blockIdx.x * 256 + tid;                    // 40960 exact
    float s = 0.0f;
#pragma unroll
    for (int ks = 0; ks < KS_; ++ks) s += partials[(size_t)ks * (B_ * N_) + g];
    s *= scale;
    float sq = s * s;
    dst[g] = sq / (1.0f + sq) * s / (sqrtf(sq) + 1e-5f);
}

// ---------------------------------------------------------------------------
// bupd: per block (c, r0-tile of 64):
//   bij[r][n] (+)= (1/B) sum_b v[b][n] * tT[c][b][r]
//   E[r][n] = exp(bij); nsum[n] += sum_r E   (max-free softmax)
// v slice staged in LDS; tT reads coalesced, read exactly once grid-wide.
__launch_bounds__(256)
__global__ void bupd_kernel(const float* __restrict__ v, const float* __restrict__ tT,
                            float* __restrict__ bij, float* __restrict__ E,
                            float* __restrict__ nsum, int accumulate) {
    __shared__ float vs[B_ * 16];     // [b][d] 16 KB
    __shared__ float red[16 * 256];   // [d][tid] 16 KB
    int tid = threadIdx.x;
    int c = blockIdx.x % 10;
    int r0 = (blockIdx.x / 10) * 64;
    int rsub = tid & 63, bs = tid >> 6;

    for (int q = tid; q < 1024; q += 256) {
        int b = q >> 2, d4 = q & 3;
        ((float4*)vs)[q] = *(const float4*)(v + (size_t)b * N_ + c * 16 + d4 * 4);
    }
    __syncthreads();

    float acc[16];
#pragma unroll
    for (int d = 0; d < 16; ++d) acc[d] = 0.0f;

    const float* tp = tT + ((size_t)c * B_ + bs * 64) * R_ + r0 + rsub;
    for (int bb = 0; bb < 64; ++bb) {
        float tv = tp[(size_t)bb * R_];                     // coalesced across wave
        const float4* vrow = (const float4*)(vs + (bs * 64 + bb) * 16); // uniform bcast
        float4 v0 = vrow[0], v1 = vrow[1], v2 = vrow[2], v3 = vrow[3];
        acc[0]  = fmaf(tv, v0.x, acc[0]);  acc[1]  = fmaf(tv, v0.y, acc[1]);
        acc[2]  = fmaf(tv, v0.z, acc[2]);  acc[3]  = fmaf(tv, v0.w, acc[3]);
        acc[4]  = fmaf(tv, v1.x, acc[4]);  acc[5]  = fmaf(tv, v1.y, acc[5]);
        acc[6]  = fmaf(tv, v1.z, acc[6]);  acc[7]  = fmaf(tv, v1.w, acc[7]);
        acc[8]  = fmaf(tv, v2.x, acc[8]);  acc[9]  = fmaf(tv, v2.y, acc[9]);
        acc[10] = fmaf(tv, v2.z, acc[10]); acc[11] = fmaf(tv, v2.w, acc[11]);
        acc[12] = fmaf(tv, v3.x, acc[12]); acc[13] = fmaf(tv, v3.y, acc[13]);
        acc[14] = fmaf(tv, v3.z, acc[14]); acc[15] = fmaf(tv, v3.w, acc[15]);
    }
#pragma unroll
    for (int d = 0; d < 16; ++d) red[d * 256 + tid] = acc[d];
    __syncthreads();

#pragma unroll
    for (int j = 0; j < 4; ++j) {
        int q = tid + 256 * j;
        int rr = q & 63, d = q >> 6;                   // d uniform per wave
        const float* rp = red + d * 256 + rr;
        float s = (rp[0] + rp[64] + rp[128] + rp[192]) * (1.0f / B_);
        int o = (r0 + rr) * N_ + c * 16 + d;
        if (accumulate) s += bij[o];
        bij[o] = s;
        float ex = __expf(s);                          // max-free: |bij| = O(1)
        E[o] = ex;
#pragma unroll
        for (int off = 32; off > 0; off >>= 1) ex += __shfl_down(ex, off, 64);
        if (rr == 0) atomicAdd(&nsum[c * 16 + d], ex);
    }
}

// ---------------------------------------------------------------------------
extern "C" void kernel_launch(void* const* d_in, const int* in_sizes, int n_in,
                              void* d_out, int out_size, void* d_ws, size_t ws_size,
                              hipStream_t stream) {
    (void)in_sizes; (void)n_in; (void)out_size; (void)ws_size;
    const float* u = (const float*)d_in[0];
    const float* W = (const float*)d_in[1];
    float* out = (float*)d_out;
    float* ws = (float*)d_ws;

    float* Wsum     = ws + OFF_WSUM;
    float* tT       = ws + OFF_TT;
    float* v        = ws + OFF_V;
    float* bij      = ws + OFF_BIJ;
    float* E        = ws + OFF_E;
    float* nsumA    = ws + OFF_NSA;
    float* nsumB    = ws + OFF_NSB;
    float* partials = ws + OFF_PART;

    // 8 dispatches
    gemm_kernel<0><<<872, 256, 0, stream>>>(u, W, nullptr, nullptr, partials,
                                            Wsum, nsumA, nsumB);
    rsv_kernel<1><<<520, 256, 0, stream>>>(partials, v, 1.0f / 1152.0f, u, Wsum, tT);
    bupd_kernel<<<180, 256, 0, stream>>>(v, tT, bij, E, nsumA, 0);

    gemm_kernel<1><<<512, 256, 0, stream>>>(u, W, E, nsumA, partials,
                                            nullptr, nullptr, nullptr);
    rsv_kernel<0><<<160, 256, 0, stream>>>(partials, v, 1.0f, nullptr, nullptr, nullptr);
    bupd_kernel<<<180, 256, 0, stream>>>(v, tT, bij, E, nsumB, 1);

    gemm_kernel<1><<<512, 256, 0, stream>>>(u, W, E, nsumB, partials,
                                            nullptr, nullptr, nullptr);
    rsv_kernel<0><<<160, 256, 0, stream>>>(partials, out, 1.0f, nullptr, nullptr, nullptr);
}